// Round 10
// baseline (103.578 us; speedup 1.0000x reference)
//
#include <hip/hip_runtime.h>
#include <hip/hip_bf16.h>
#include <stdint.h>

typedef __attribute__((ext_vector_type(8))) __bf16 bf16x8;
typedef __attribute__((ext_vector_type(4))) float f32x4;
typedef __attribute__((ext_vector_type(8))) unsigned short u16x8;

__device__ __forceinline__ unsigned short f2bf(float f) {
    unsigned u = __builtin_bit_cast(unsigned, f);
    return (unsigned short)((u + 0x7fffu + ((u >> 16) & 1u)) >> 16);  // RNE
}

__device__ __forceinline__ void glds16(const void* g, void* l) {
    __builtin_amdgcn_global_load_lds(
        (const __attribute__((address_space(1))) unsigned int*)(uintptr_t)g,
        (__attribute__((address_space(3))) unsigned int*)l, 16, 0, 0);
}

#define VMCNT(n) asm volatile("s_waitcnt vmcnt(" #n ")" ::: "memory")
#define BAR()                                  \
    do {                                       \
        asm volatile("" ::: "memory");         \
        __builtin_amdgcn_s_barrier();          \
        asm volatile("" ::: "memory");         \
    } while (0)

#define MFMA16(a, b, c) __builtin_amdgcn_mfma_f32_16x16x32_bf16((a), (b), (c), 0, 0, 0)

// ---------------------------------------------------------------------------
// Kernel 1 (fused prep, VERIFIED R9): blocks [0,1024) build W; rest cvt x.
// Build: block (bo, bn4, wn) computes slabs IN LDS, 256x64x16 MFMA patch,
// stores 4 complete W rows.  W[(o01*64+o23)][(a01*64+a23)].
// factors layout: [b][j][i][o][r] strides b:512 j:128 i:16 o:2 r:1
// ---------------------------------------------------------------------------
__global__ __launch_bounds__(256) void prep_fused(const float* __restrict__ factors,
                                                  const float* __restrict__ cores,
                                                  const float4* __restrict__ xin,
                                                  ushort4* __restrict__ xb,
                                                  unsigned short* __restrict__ Wt) {
    if (blockIdx.x >= 1024) {
        int i = (blockIdx.x - 1024) * 256 + threadIdx.x;
        float4 v = xin[i];
        ushort4 o;
        o.x = f2bf(v.x); o.y = f2bf(v.y); o.z = f2bf(v.z); o.w = f2bf(v.w);
        xb[i] = o;
        return;
    }
    __shared__ unsigned short As2[256 * 40];
    __shared__ unsigned short Bs2[64 * 40];
    __shared__ unsigned short lbuf[4 * 64 * 72];
    const int tid = threadIdx.x, lane = tid & 63, w = tid >> 6;
    const int bo = blockIdx.x >> 6, bn4 = (blockIdx.x >> 2) & 15, wn = blockIdx.x & 3;

    {   // As2 row tid: val = F0[a0,o0,r0]*F1[a1,o1,r1], k = b*4+q
        int o01 = bo * 4 + (tid >> 6), a01 = tid & 63;
        int o0 = o01 >> 3, o1 = o01 & 7, a0 = a01 >> 3, a1 = a01 & 7;
#pragma unroll
        for (int k = 0; k < 16; ++k) {
            int b = k >> 2, q = k & 3, r0 = q >> 1, r1 = q & 1;
            float v = factors[b*512 +   0 + a0*16 + o0*2 + r0]
                    * factors[b*512 + 128 + a1*16 + o1*2 + r1];
            As2[tid * 40 + k] = f2bf(v);
            As2[tid * 40 + 16 + k] = 0;
        }
    }
    {   // Bs2: 64 rows (a23) x 16 k; o23 fixed = bn4*4+wn
        int o23 = bn4 * 4 + wn, o2 = o23 >> 3, o3 = o23 & 7;
#pragma unroll
        for (int rep = 0; rep < 4; ++rep) {
            int task = rep * 256 + tid;
            int n = task >> 4, k = task & 15;
            int a2 = n >> 3, a3 = n & 7;
            int b = k >> 2, q = k & 3, r0 = q >> 1, r1 = q & 1;
            float s = 0.f;
#pragma unroll
            for (int r2 = 0; r2 < 2; ++r2)
#pragma unroll
                for (int r3 = 0; r3 < 2; ++r3)
                    s += factors[b*512 + 256 + a2*16 + o2*2 + r2]
                       * factors[b*512 + 384 + a3*16 + o3*2 + r3]
                       * cores[b*16 + r3*8 + r2*4 + r1*2 + r0];
            Bs2[n * 40 + k] = f2bf(s);
            Bs2[n * 40 + 16 + k] = 0;
        }
    }
    __syncthreads();

    const int fr = lane & 15, fh = lane >> 4;
    bf16x8 af[4], bf_[4];
#pragma unroll
    for (int mf = 0; mf < 4; ++mf)
        af[mf] = *(const bf16x8*)&As2[(w * 64 + mf * 16 + fr) * 40 + fh * 8];
#pragma unroll
    for (int nf = 0; nf < 4; ++nf)
        bf_[nf] = *(const bf16x8*)&Bs2[(nf * 16 + fr) * 40 + fh * 8];
    f32x4 acc[4][4] = {};
#pragma unroll
    for (int mf = 0; mf < 4; ++mf)
#pragma unroll
        for (int nf = 0; nf < 4; ++nf)
            acc[mf][nf] = MFMA16(af[mf], bf_[nf], acc[mf][nf]);
#pragma unroll
    for (int mf = 0; mf < 4; ++mf)
#pragma unroll
        for (int nf = 0; nf < 4; ++nf)
#pragma unroll
            for (int j = 0; j < 4; ++j)
                lbuf[w * 4608 + (mf * 16 + fh * 4 + j) * 72 + nf * 16 + fr] =
                    f2bf(acc[mf][nf][j]);
    const int o = (bo * 4 + w) * 64 + bn4 * 4 + wn;
    unsigned short* dst = Wt + (size_t)o * 4096;
#pragma unroll
    for (int i = 0; i < 8; ++i) {
        int c = i * 64 + lane;
        *(u16x8*)&dst[c * 8] =
            *(const u16x8*)&lbuf[w * 4608 + (c >> 3) * 72 + (c & 7) * 8];
    }
}

// ---------------------------------------------------------------------------
// Kernel 2: C[1024][4096] = A[1024][4096] * Wt^T.  v9 — A-in-registers:
//   R7 skeleton (64M x 128N, BK=64, 4 waves 2x2, wave 32x64, acc 2x4,
//   grid 512 = 2 desync blocks/CU) with A-fragments loaded DIRECTLY
//   global->VGPR (lane reads A[row=bm*64+wm*32+m*16+fr][t*64+kk*32+fh*8]).
//   LDS carries only B: 48 KB/block-step vs R7's 72 (-33% on the measured
//   ~67%-busy LDS pipe); A rides the idle VMEM path (L1/L2: wn-pair shares
//   rows via L1, 4 same-bm blocks per XCD share the panel via L2).
//   2 B-bufs x 16 KB (depth-1; phase ~600cyc > L2 latency), counted VMCNT(8)
//   (4 A-loads + 4 B-glds per phase; never 0 in loop), 2-phase unroll with
//   named A-reg sets E/O (rule 20: no runtime-indexed reg arrays).
//   B swizzle/epilogue/XCD map verbatim R7 (conflicts measured 0).
// ---------------------------------------------------------------------------
__global__ __launch_bounds__(256, 2) void gemm_areg(const unsigned short* __restrict__ A,
                                                    const unsigned short* __restrict__ Bt,
                                                    float* __restrict__ C) {
    constexpr int K = 4096;
    constexpr int N = 4096;
    constexpr int BK = 64;
    __shared__ alignas(16) char lds[2][16384];   // [buf][B 16KB]
    const int tid = threadIdx.x;
    const int lane = tid & 63, w = tid >> 6;
    const int wm = w >> 1, wn = w & 1;
    const int xcd = blockIdx.x & 7, r = blockIdx.x >> 3;  // r 0..63
    const int bn = xcd * 4 + (r & 3);            // 0..31
    const int bm = r >> 2;                       // 0..15

    // --- B staging: 1024 16B slots (4/thread), 8 chunks per 128B row ---
    const unsigned short* gB[4];
    int lBoff[4];
#pragma unroll
    for (int i = 0; i < 4; ++i) {
        int cs = i * 256 + tid;
        int row = cs >> 3;
        int c = (cs & 7) ^ ((row >> 1) & 7);     // source-side XOR swizzle
        gB[i] = Bt + (size_t)(bn * 128 + row) * K + c * 8;
        lBoff[i] = i * 4096 + w * 1024;          // wave-uniform base (+lane*16 HW)
    }

#define STAGEB(buf, tt)                                            \
    do {                                                           \
        glds16(gB[0] + (tt) * BK, &lds[buf][lBoff[0]]);            \
        glds16(gB[1] + (tt) * BK, &lds[buf][lBoff[1]]);            \
        glds16(gB[2] + (tt) * BK, &lds[buf][lBoff[2]]);            \
        glds16(gB[3] + (tt) * BK, &lds[buf][lBoff[3]]);            \
    } while (0)

    // --- A fragment pointers (global, per-lane) ---
    const int fr = lane & 15, fh = lane >> 4;
    const unsigned short* a00 = A + (size_t)(bm * 64 + wm * 32 + fr) * K + fh * 8;
    const unsigned short* a01 = a00 + 32;        // kk=1
    const unsigned short* a10 = a00 + (size_t)16 * K;   // m=1
    const unsigned short* a11 = a10 + 32;

    bf16x8 aE00, aE01, aE10, aE11;               // even-phase A frags
    bf16x8 aO00, aO01, aO10, aO11;               // odd-phase A frags
#define ALOAD(S, tt)                                               \
    do {                                                           \
        a##S##00 = *(const bf16x8*)(a00 + (tt) * BK);              \
        a##S##01 = *(const bf16x8*)(a01 + (tt) * BK);              \
        a##S##10 = *(const bf16x8*)(a10 + (tt) * BK);              \
        a##S##11 = *(const bf16x8*)(a11 + (tt) * BK);              \
    } while (0)

    // --- B fragment read offsets (swizzled) ---
    const int sk = (fr >> 1) & 7;
    const int boff0 = (wn * 64 + fr) * 128 + ((fh ^ sk) << 4);           // kk=0
    const int boff1 = (wn * 64 + fr) * 128 + (((4 + fh) ^ sk) << 4);     // kk=1

    f32x4 acc[2][4] = {};

#define CHALF(base, bof, A0, A1)                                   \
    do {                                                           \
        bf16x8 b0 = *(const bf16x8*)((base) + (bof));              \
        bf16x8 b1 = *(const bf16x8*)((base) + (bof) + 2048);       \
        bf16x8 b2 = *(const bf16x8*)((base) + (bof) + 4096);       \
        bf16x8 b3 = *(const bf16x8*)((base) + (bof) + 6144);       \
        acc[0][0] = MFMA16(A0, b0, acc[0][0]);                     \
        acc[0][1] = MFMA16(A0, b1, acc[0][1]);                     \
        acc[0][2] = MFMA16(A0, b2, acc[0][2]);                     \
        acc[0][3] = MFMA16(A0, b3, acc[0][3]);                     \
        acc[1][0] = MFMA16(A1, b0, acc[1][0]);                     \
        acc[1][1] = MFMA16(A1, b1, acc[1][1]);                     \
        acc[1][2] = MFMA16(A1, b2, acc[1][2]);                     \
        acc[1][3] = MFMA16(A1, b3, acc[1][3]);                     \
    } while (0)

#define COMPUTE(buf, S)                                            \
    do {                                                           \
        const char* base_ = &lds[buf][0];                          \
        CHALF(base_, boff0, a##S##00, a##S##10);                   \
        CHALF(base_, boff1, a##S##01, a##S##11);                   \
    } while (0)

    // --- pipelined main loop: depth-1, counted vmcnt, 2-phase unroll ---
    ALOAD(E, 0);
    STAGEB(0, 0);
    for (int t = 0; t < 62; t += 2) {            // 31 iterations: phases 0..61
        ALOAD(O, t + 1); STAGEB(1, t + 1);
        VMCNT(8); BAR(); COMPUTE(0, E); BAR();   // phase t (even)
        ALOAD(E, t + 2); STAGEB(0, t + 2);
        VMCNT(8); BAR(); COMPUTE(1, O); BAR();   // phase t+1 (odd)
    }
    ALOAD(O, 63); STAGEB(1, 63);
    VMCNT(8); BAR(); COMPUTE(0, E); BAR();       // phase 62
    VMCNT(0); BAR(); COMPUTE(1, O);              // phase 63

    // --- epilogue: plain coalesced stores ---
    const int crow0 = bm * 64 + wm * 32 + fh * 4;
    const int ccol0 = bn * 128 + wn * 64 + fr;
#pragma unroll
    for (int m = 0; m < 2; ++m)
#pragma unroll
        for (int n = 0; n < 4; ++n)
#pragma unroll
            for (int j = 0; j < 4; ++j)
                C[(size_t)(crow0 + m * 16 + j) * N + (ccol0 + n * 16)] = acc[m][n][j];
#undef STAGEB
#undef ALOAD
#undef CHALF
#undef COMPUTE
}

// ---------------------------------------------------------------------------
extern "C" void kernel_launch(void* const* d_in, const int* in_sizes, int n_in,
                              void* d_out, int out_size, void* d_ws, size_t ws_size,
                              hipStream_t stream) {
    const float* inputs  = (const float*)d_in[0];   // [1024, 4096] f32
    const float* cores   = (const float*)d_in[1];   // [4, 16] f32
    const float* factors = (const float*)d_in[2];   // [4,4,8,8,2] f32
    float* out = (float*)d_out;                     // [1024, 4096] f32

    char* ws = (char*)d_ws;
    unsigned short* xb = (unsigned short*)ws;                       //  8 MB bf16 x
    unsigned short* Wt = (unsigned short*)(ws + (8u << 20));        // 32 MB bf16 W^T

    prep_fused<<<5120, 256, 0, stream>>>(factors, cores,
                                         (const float4*)inputs, (ushort4*)xb, Wt);
    gemm_areg<<<512, 256, 0, stream>>>(xb, Wt, out);
}